// Round 2
// baseline (341.360 us; speedup 1.0000x reference)
//
#include <hip/hip_runtime.h>

// PINNLayer — NN=100000, NE=3200000. fp32 in, fp32 out.
// d_out fp32: [ result (NN) | out2 (NE,3) rows = [src,dst,val] ].
//
// Round-7: round-6's accum_f still re-read the whole 51.2MB record stream once
// per window (7x = 358MB L3 traffic, 12/13 of it discarded by window checks).
// New full path buckets records BY WINDOW at production time:
//   P1 edge_scatter: conv + out2 + scatter {node,val} records into per-window
//      buckets (LDS histogram + 1 global atomicAdd per bucket per block for
//      reservation; 4 edges/thread for fat write chunks). Bounded capacity
//      with overflow arena => correct under any skew.
//   P2 accum_b: grid = 13 windows x 20 slices; 64KB LDS (2 blocks/CU);
//      each record read EXACTLY ONCE, no window checks; flush = plain
//      coalesced float4 stores of per-slice partials. Zero global atomics.
//   P3 node_final_b: reduce 20 partials + compose.
// Fallback to the proven round-5 pipeline if ws_size too small.

#define WSH  13
#define WSZ  8192       // nodes per window (64KB LDS for two fp32 tables)
#define SL   20         // slices per window  -> grid 13*20 = 260 blocks
#define EPT  4          // edges per thread in edge_scatter
#define MAXW 32         // max windows supported by the LDS counter arrays

// old-path constants (fallback)
#define OWSH 13
#define OWSZ 8192
#define OPB  16
#define OFPS 8192.0f
#define OQBIAS (1 << 20)
#define OQCLMP ((1 << 19) - 1)

// ---------------------------------------------------------------------------
// prep: conc gather; zero bucket tails (full path) or acc (fallback path).
__global__ __launch_bounds__(256) void prep(
    const float* __restrict__ od,
    float* __restrict__ conc,
    unsigned long long* __restrict__ acc,
    unsigned* __restrict__ tails,      // padded: tail[i] at tails[i<<4]; [64<<4]=ovf tail
    int n_nodes)
{
    if (blockIdx.x == 0 && tails && threadIdx.x < 65)
        tails[(size_t)threadIdx.x << 4] = 0u;
    int n = blockIdx.x * blockDim.x + threadIdx.x;
    if (n >= n_nodes) return;
    conc[n] = od[(long long)n * 48 + 45];   // origin_data[n,15,0]
    if (acc) acc[n] = 0ULL;
}

// ---------------------------------------------------------------------------
// P1 (full): conv + out2 + bucketed record scatter.
// val[e] = b + sum_{j<36} flow[e*12+j] * w_re[j],
//   w_re[kh*12+kw*4+i] = conv_w[i*9+kh*3+kw]
// A-record {s, val} -> bucketA[s>>WSH];  B-record {d, val*conc[s]} -> bucketB[d>>WSH]
__global__ __launch_bounds__(256) void edge_scatter(
    const float* __restrict__ flow, const int* __restrict__ ei,
    const float* __restrict__ conv_w, const float* __restrict__ conv_b,
    const float* __restrict__ conc,
    float* __restrict__ out2,
    uint2* __restrict__ recA, uint2* __restrict__ recB,
    uint2* __restrict__ ovf,
    unsigned* __restrict__ tails,
    int n_edges, unsigned cap, unsigned ocap)
{
    __shared__ float w[40];
    __shared__ unsigned cnt[2 * MAXW];
    __shared__ unsigned bas[2 * MAXW];
    const int t = threadIdx.x;
    if (t < 36) {
        int i  = t & 3;
        int kw = (t >> 2) % 3;
        int kh = t / 12;
        w[t] = conv_w[i * 9 + kh * 3 + kw];
    }
    if (t == 36) w[36] = conv_b[0];
    if (t < 2 * MAXW) cnt[t] = 0u;
    __syncthreads();

    const long long eb = (long long)blockIdx.x * (256 * EPT) + t;
    int      sN[EPT], dN[EPT];
    float    vA[EPT], vB[EPT];
    unsigned pA_[EPT], pB_[EPT];
    bool     live[EPT];

#pragma unroll
    for (int k = 0; k < EPT; ++k) {
        long long e = eb + (long long)k * 256;
        live[k] = false;
        if (e < n_edges) {
            int s = ei[e];
            int d = ei[n_edges + e];
            const float4* fp = (const float4*)(flow + e * 12);
            float acc = w[36];
#pragma unroll
            for (int q = 0; q < 9; ++q) {
                float4 v = fp[q];
                acc = fmaf(v.x, w[q * 4 + 0], acc);
                acc = fmaf(v.y, w[q * 4 + 1], acc);
                acc = fmaf(v.z, w[q * 4 + 2], acc);
                acc = fmaf(v.w, w[q * 4 + 3], acc);
            }
            float cs = conc[s];                 // L2-resident gather (400KB)
            float* o = out2 + e * 3;
            o[0] = (float)s;
            o[1] = (float)d;
            o[2] = acc;
            sN[k] = s; dN[k] = d;
            vA[k] = acc; vB[k] = acc * cs;
            if (s != d) {
                live[k] = true;
                pA_[k] = atomicAdd(&cnt[(unsigned)s >> WSH], 1u);
                pB_[k] = atomicAdd(&cnt[MAXW + ((unsigned)d >> WSH)], 1u);
            }
        }
    }
    __syncthreads();
    if (t < 2 * MAXW && cnt[t])
        bas[t] = atomicAdd(&tails[(size_t)t << 4], cnt[t]);
    __syncthreads();

#pragma unroll
    for (int k = 0; k < EPT; ++k) {
        if (!live[k]) continue;
        {   // A record
            unsigned wa = (unsigned)sN[k] >> WSH;
            unsigned sa = bas[wa] + pA_[k];
            uint2 r; r.x = (unsigned)sN[k]; r.y = __float_as_uint(vA[k]);
            if (sa < cap) {
                recA[(size_t)wa * cap + sa] = r;
            } else {
                unsigned os = atomicAdd(&tails[(size_t)64 << 4], 1u);
                if (os < ocap) ovf[os] = r;          // flag bit31 = 0 -> A
            }
        }
        {   // B record
            unsigned wb = (unsigned)dN[k] >> WSH;
            unsigned sb = bas[MAXW + wb] + pB_[k];
            uint2 r; r.x = (unsigned)dN[k]; r.y = __float_as_uint(vB[k]);
            if (sb < cap) {
                recB[(size_t)wb * cap + sb] = r;
            } else {
                r.x |= 0x80000000u;                  // flag bit31 = 1 -> B
                unsigned os = atomicAdd(&tails[(size_t)64 << 4], 1u);
                if (os < ocap) ovf[os] = r;
            }
        }
    }
}

// ---------------------------------------------------------------------------
// P2 (full): each (window, slice) block reads its bucket slice exactly once.
__global__ __launch_bounds__(1024) void accum_b(
    const uint2* __restrict__ recA, const uint2* __restrict__ recB,
    const uint2* __restrict__ ovf,
    const unsigned* __restrict__ tails,
    float* __restrict__ pA, float* __restrict__ pB,
    unsigned cap, unsigned ocap)
{
    __shared__ float tA[WSZ];
    __shared__ float tB[WSZ];

    const int w  = blockIdx.x / SL;
    const int sl = blockIdx.x % SL;
    const int t  = threadIdx.x;

    for (int i = t; i < WSZ; i += 1024) { tA[i] = 0.f; tB[i] = 0.f; }
    __syncthreads();

    {   // A bucket slice
        unsigned nA = min(tails[(size_t)w << 4], cap);
        const uint2* r = recA + (size_t)w * cap;
        size_t i0 = (size_t)nA * sl / SL, i1 = (size_t)nA * (sl + 1) / SL;
        for (size_t i = i0 + t; i < i1; i += 1024) {
            uint2 q = r[i];
            atomicAdd(&tA[q.x & (WSZ - 1)], __uint_as_float(q.y));
        }
    }
    {   // B bucket slice
        unsigned nB = min(tails[(size_t)(MAXW + w) << 4], cap);
        const uint2* r = recB + (size_t)w * cap;
        size_t i0 = (size_t)nB * sl / SL, i1 = (size_t)nB * (sl + 1) / SL;
        for (size_t i = i0 + t; i < i1; i += 1024) {
            uint2 q = r[i];
            atomicAdd(&tB[q.x & (WSZ - 1)], __uint_as_float(q.y));
        }
    }
    {   // overflow arena (empty for non-adversarial inputs)
        unsigned no = min(tails[(size_t)64 << 4], ocap);
        if (no) {
            size_t i0 = (size_t)no * sl / SL, i1 = (size_t)no * (sl + 1) / SL;
            for (size_t i = i0 + t; i < i1; i += 1024) {
                uint2 q = ovf[i];
                unsigned node = q.x & 0x7fffffffu;
                if ((int)(node >> WSH) == w) {
                    if (q.x >> 31) atomicAdd(&tB[node & (WSZ - 1)], __uint_as_float(q.y));
                    else           atomicAdd(&tA[node & (WSZ - 1)], __uint_as_float(q.y));
                }
            }
        }
    }
    __syncthreads();

    // Flush: plain coalesced float4 stores — no atomics.
    float* dA = pA + ((size_t)blockIdx.x << WSH);
    float* dB = pB + ((size_t)blockIdx.x << WSH);
    for (int i = t; i < (WSZ >> 2); i += 1024) {
        ((float4*)dA)[i] = ((const float4*)tA)[i];
        ((float4*)dB)[i] = ((const float4*)tB)[i];
    }
}

// ---------------------------------------------------------------------------
// P3 (full): reduce SL partials and compose result.
__global__ __launch_bounds__(256) void node_final_b(
    const float* __restrict__ od,
    const float* __restrict__ conc,
    const float* __restrict__ pA,
    const float* __restrict__ pB,
    float* __restrict__ out, int n_nodes)
{
    int n = blockIdx.x * blockDim.x + threadIdx.x;
    if (n >= n_nodes) return;

    const int w = n >> WSH, i = n & (WSZ - 1);
    size_t base = ((size_t)(w * SL) << WSH) + i;
    float a = 0.f, b = 0.f;
#pragma unroll
    for (int sl = 0; sl < SL; ++sl) {
        a += pA[base + ((size_t)sl << WSH)];
        b += pB[base + ((size_t)sl << WSH)];
    }

    long long bi = (long long)n * 48 + 45;
    float c  = conc[n];
    float p  = od[bi + 1];
    float is = 1.0f / od[bi + 2];

    float r = c;
    if (n != n_nodes - 1)
        r += (b - a * c) * is + 0.0052f * p * is;
    out[n] = r;
}

// ---------------------------------------------------------------------------
// Fallback path (round-5 proven): flat records + windowed scan + u64 atomics.
__global__ __launch_bounds__(256) void edge_conv_o(
    const float* __restrict__ flow, const int* __restrict__ ei,
    const float* __restrict__ conv_w, const float* __restrict__ conv_b,
    float* __restrict__ out2, int n_edges)
{
    __shared__ float w[40];
    int t = threadIdx.x;
    if (t < 36) {
        int i  = t & 3;
        int kw = (t >> 2) % 3;
        int kh = t / 12;
        w[t] = conv_w[i * 9 + kh * 3 + kw];
    }
    if (t == 36) w[36] = conv_b[0];
    __syncthreads();

    int e = blockIdx.x * blockDim.x + t;
    if (e >= n_edges) return;

    const float4* fp = (const float4*)(flow + (long long)e * 12);
    float acc = w[36];
#pragma unroll
    for (int q = 0; q < 9; ++q) {
        float4 v = fp[q];
        acc = fmaf(v.x, w[q * 4 + 0], acc);
        acc = fmaf(v.y, w[q * 4 + 1], acc);
        acc = fmaf(v.z, w[q * 4 + 2], acc);
        acc = fmaf(v.w, w[q * 4 + 3], acc);
    }

    float* o = out2 + (long long)e * 3;
    o[0] = (float)ei[e];
    o[1] = (float)ei[n_edges + e];
    o[2] = acc;
}

__global__ __launch_bounds__(1024) void accum_o(
    const float* __restrict__ out2,
    const float* __restrict__ conc,
    unsigned long long* __restrict__ acc,
    int n_edges, int n_nodes)
{
    __shared__ float tA[OWSZ];
    __shared__ float tB[OWSZ];

    const int w    = blockIdx.x / OPB;
    const int sl   = blockIdx.x % OPB;
    const int base = w << OWSH;

    for (int i = threadIdx.x; i < OWSZ; i += 1024) { tA[i] = 0.f; tB[i] = 0.f; }
    __syncthreads();

    const long long e0 = (long long)sl * n_edges / OPB;
    const long long e1 = (long long)(sl + 1) * n_edges / OPB;
    for (long long e = e0 + threadIdx.x; e < e1; e += 1024) {
        const float* r = out2 + e * 3;
        float fs = r[0], fd = r[1], v = r[2];
        int s = (int)fs, d = (int)fd;
        if (s == d) continue;
        if ((s >> OWSH) == w) atomicAdd(&tA[s - base], v);
        if ((d >> OWSH) == w) atomicAdd(&tB[d - base], v * conc[s]);
    }
    __syncthreads();

    for (int i = threadIdx.x; i < OWSZ; i += 1024) {
        int n = base + i;
        if (n >= n_nodes) continue;
        float a = tA[i], b = tB[i];
        if (a == 0.f && b == 0.f) continue;
        int qa = __float2int_rn(a * OFPS);
        int qb = __float2int_rn(b * OFPS);
        qa = min(max(qa, -OQCLMP), OQCLMP);
        qb = min(max(qb, -OQCLMP), OQCLMP);
        unsigned long long enc =
            ((unsigned long long)(unsigned)(qa + OQBIAS) << 37) +
            ((unsigned long long)(unsigned)(qb + OQBIAS) << 10) + 1ULL;
        atomicAdd(acc + n, enc);
    }
}

__global__ __launch_bounds__(256) void node_final_o(
    const float* __restrict__ od,
    const float* __restrict__ conc,
    const unsigned long long* __restrict__ acc,
    float* __restrict__ out, int n_nodes)
{
    int n = blockIdx.x * blockDim.x + threadIdx.x;
    if (n >= n_nodes) return;

    unsigned long long t = acc[n];
    long long cnt = (long long)(t & 1023ULL);
    unsigned long long t2 = t >> 10;
    long long sbr = (long long)(t2 & ((1ULL << 27) - 1));
    long long sar = (long long)(t2 >> 27);
    float a = (float)(sar - cnt * OQBIAS) * (1.0f / OFPS);
    float b = (float)(sbr - cnt * OQBIAS) * (1.0f / OFPS);

    long long bi = (long long)n * 48 + 45;
    float c  = conc[n];
    float p  = od[bi + 1];
    float is = 1.0f / od[bi + 2];

    float r = c;
    if (n != n_nodes - 1)
        r += (b - a * c) * is + 0.0052f * p * is;
    out[n] = r;
}

// ---------------------------------------------------------------------------
extern "C" void kernel_launch(void* const* d_in, const int* in_sizes, int n_in,
                              void* d_out, int out_size, void* d_ws, size_t ws_size,
                              hipStream_t stream) {
    const float* od   = (const float*)d_in[0];
    const float* flow = (const float*)d_in[1];
    const float* cw   = (const float*)d_in[2];
    const float* cb   = (const float*)d_in[3];
    const int*   ei   = (const int*)d_in[4];

    const int n_nodes = in_sizes[0] / 48;
    const int n_edges = in_sizes[4] / 2;

    float* out_res = (float*)d_out;        // (NN,)
    float* out2    = out_res + n_nodes;    // (NE,3)

    dim3 blk(256);
    dim3 grid_nodes((n_nodes + 255) / 256);

    // --- full-path workspace layout -------------------------------------
    const int n_win = (n_nodes + WSZ - 1) >> WSH;                 // 13
    const unsigned cap  = (unsigned)(n_edges / (n_win > 0 ? n_win : 1))
                        + (unsigned)(n_edges / 8) + 1024u;        // expected + slack
    const unsigned ocap = (unsigned)(2ULL * (unsigned long long)n_edges);

    size_t off = 0;
    size_t o_conc  = off; off += (((size_t)n_nodes * 4) + 255) & ~255ULL;
    size_t o_tails = off; off += (65 * 16 * 4 + 255) & ~255ULL;   // padded tails
    size_t o_recA  = off; off += (((size_t)n_win * cap * 8) + 255) & ~255ULL;
    size_t o_recB  = off; off += (((size_t)n_win * cap * 8) + 255) & ~255ULL;
    size_t o_ovf   = off; off += (((size_t)ocap * 8) + 255) & ~255ULL;
    size_t o_pA    = off; off += (((size_t)n_win * SL * WSZ * 4) + 255) & ~255ULL;
    size_t o_pB    = off; off += (((size_t)n_win * SL * WSZ * 4) + 255) & ~255ULL;
    const bool full = (ws_size >= off) && (n_win <= MAXW);

    float* conc = (float*)((char*)d_ws + o_conc);

    if (full) {
        unsigned* tails = (unsigned*)((char*)d_ws + o_tails);
        uint2* recA = (uint2*)((char*)d_ws + o_recA);
        uint2* recB = (uint2*)((char*)d_ws + o_recB);
        uint2* ovf  = (uint2*)((char*)d_ws + o_ovf);
        float* pA   = (float*)((char*)d_ws + o_pA);
        float* pB   = (float*)((char*)d_ws + o_pB);

        dim3 grid_es((n_edges + 256 * EPT - 1) / (256 * EPT));    // 3125

        prep<<<grid_nodes, blk, 0, stream>>>(od, conc, nullptr, tails, n_nodes);
        edge_scatter<<<grid_es, blk, 0, stream>>>(flow, ei, cw, cb, conc,
                                                  out2, recA, recB, ovf, tails,
                                                  n_edges, cap, ocap);
        accum_b<<<dim3(n_win * SL), dim3(1024), 0, stream>>>(
            recA, recB, ovf, tails, pA, pB, cap, ocap);
        node_final_b<<<grid_nodes, blk, 0, stream>>>(od, conc, pA, pB,
                                                     out_res, n_nodes);
    } else {
        // round-5 pipeline
        unsigned long long* acc =
            (unsigned long long*)((char*)d_ws + (((size_t)n_nodes * 4 + 7) / 8 * 8));
        const int n_win_o = (n_nodes + OWSZ - 1) >> OWSH;
        dim3 grid_edges((n_edges + 255) / 256);

        prep<<<grid_nodes, blk, 0, stream>>>(od, conc, acc, nullptr, n_nodes);
        edge_conv_o<<<grid_edges, blk, 0, stream>>>(flow, ei, cw, cb, out2, n_edges);
        accum_o<<<dim3(n_win_o * OPB), dim3(1024), 0, stream>>>(
            out2, conc, acc, n_edges, n_nodes);
        node_final_o<<<grid_nodes, blk, 0, stream>>>(od, conc, acc,
                                                     out_res, n_nodes);
    }
}